// Round 8
// baseline (353.381 us; speedup 1.0000x reference)
//
#include <hip/hip_runtime.h>
#include <hip/hip_bf16.h>

#define BB 2
#define TT 2048
#define DMODEL 2048
#define NH 16
#define NKV 4
#define DH 128
#define NV 256
#define TL (TT - NV)   // 1792
#define NQKV 3072      // fused projection width: q 2048 | k 512 | v 512

typedef __bf16  bf16x8  __attribute__((ext_vector_type(8)));
typedef float   float4v __attribute__((ext_vector_type(4)));
typedef short   short8  __attribute__((ext_vector_type(8)));
typedef unsigned short ushort;

__device__ __forceinline__ float bf2f(ushort u) {
    union { float f; unsigned i; } c; c.i = ((unsigned)u) << 16; return c.f;
}
__device__ __forceinline__ ushort f2bf(float f) {
    union { float f; unsigned i; } c; c.f = f;
    unsigned r = c.i + 0x7fff + ((c.i >> 16) & 1);
    return (ushort)(r >> 16);
}
// pack two f32 -> 2x bf16 in one instr (low = a, high = b), RNE
__device__ __forceinline__ unsigned cvtpk(float a, float b) {
    unsigned r;
    asm("v_cvt_pk_bf16_f32 %0, %1, %2" : "=v"(r) : "v"(a), "v"(b));
    return r;
}

// async global->LDS, 16B per lane; LDS dest = wave-uniform base + lane*16
#define GLDS16(g, l) __builtin_amdgcn_global_load_lds( \
    (__attribute__((address_space(1))) void*)(g), \
    (__attribute__((address_space(3))) void*)(l), 16, 0, 0)

// ---------------------------------------------------------------------------
// attn job table: 51 jobs per (head-pair, batch) slice, LPT-ordered.
// Split q-tiles (nkt>=18): vision 0..3 and text 17..31 -> two KV halves.
// J_PH: 255 = whole job; else pslot_local*2 + half (half0 -> scratch partial).
// ---------------------------------------------------------------------------
#define NJOB 51
#define NSLOT 19
__device__ const short J_QT[NJOB] = {
    16,  0, 0, 1, 1, 2, 2, 3, 3, 31, 31, 30, 15,
    30, 29, 29, 28, 14, 28, 27, 27, 26, 13, 26, 25, 25, 24, 12,
    24, 23, 23, 22, 11, 22, 21, 21, 20, 10, 20, 19, 19, 18,  9,
    18, 17, 17,  8,  7,  6,  5,  4 };
__device__ const short J_K0[NJOB] = {
     0,  0,16, 0,16, 0,16, 0,16,  0, 16,  0,  0,
    16,  0,15, 0,  0, 15,  0, 14,  0,  0, 14,  0, 13,  0,  0,
    13,  0,12, 0,  0, 12,  0, 11,  0,  0, 11,  0, 10,  0,  0,
    10,  0, 9, 0,  0,  0,  0,  0 };
__device__ const short J_K1[NJOB] = {
    17, 16,32,16,32,16,32,16,32, 16, 32, 16, 16,
    31, 15,30,15, 15, 29, 14, 28, 14, 14, 27, 13, 26, 13, 13,
    25, 12,24,12, 12, 23, 11, 22, 11, 11, 21, 10, 20, 10, 10,
    19,  9,18, 9,  8,  7,  6,  5 };
__device__ const short J_PH[NJOB] = {
   255,  0, 1, 2, 3, 4, 5, 6, 7, 36, 37, 34,255,
    35, 32,33,30,255, 31, 28, 29, 26,255, 27, 24, 25, 22,255,
    23, 20,21,18,255, 19, 16, 17, 14,255, 15, 12, 13, 10,255,
    11,  8, 9,255,255,255,255,255 };

// ---------------------------------------------------------------------------
// x f32 -> bf16, 8 elems/thread
// ---------------------------------------------------------------------------
__global__ __launch_bounds__(256) void convert_x(
    const float* __restrict__ x, ushort* __restrict__ xbf)
{
    size_t i = ((size_t)blockIdx.x * 256 + threadIdx.x) * 8;
    float4v f0 = *(const float4v*)&x[i];
    float4v f1 = *(const float4v*)&x[i + 4];
    short8 h;
    h[0] = (short)f2bf(f0[0]); h[1] = (short)f2bf(f0[1]);
    h[2] = (short)f2bf(f0[2]); h[3] = (short)f2bf(f0[3]);
    h[4] = (short)f2bf(f1[0]); h[5] = (short)f2bf(f1[1]);
    h[6] = (short)f2bf(f1[2]); h[7] = (short)f2bf(f1[3]);
    *(short8*)&xbf[i] = h;
}

// ---------------------------------------------------------------------------
// Fused weight transpose+convert wq|wk|wv -> wqkvT[3072][2048] bf16.
// ---------------------------------------------------------------------------
__global__ __launch_bounds__(256) void wtrans_all(
    const float* __restrict__ wq, const float* __restrict__ wk,
    const float* __restrict__ wv, ushort* __restrict__ wT)
{
    __shared__ ushort st[64][72];
    int n0 = blockIdx.x * 64, k0 = blockIdx.y * 64;
    const float* w; int N, nn;
    if (n0 < 2048)      { w = wq; N = 2048; nn = n0; }
    else if (n0 < 2560) { w = wk; N = 512;  nn = n0 - 2048; }
    else                { w = wv; N = 512;  nn = n0 - 2560; }
    int r  = threadIdx.x >> 2;
    int c0 = (threadIdx.x & 3) * 16;
    #pragma unroll
    for (int j = 0; j < 16; j += 4) {
        float4v f = *(const float4v*)&w[(size_t)(k0 + r) * N + nn + c0 + j];
        st[c0 + j + 0][r] = f2bf(f[0]);
        st[c0 + j + 1][r] = f2bf(f[1]);
        st[c0 + j + 2][r] = f2bf(f[2]);
        st[c0 + j + 3][r] = f2bf(f[3]);
    }
    __syncthreads();
    ushort* dst = &wT[(size_t)(n0 + r) * DMODEL + k0];
    *(short8*)&dst[c0]     = *(short8*)&st[r][c0];
    *(short8*)&dst[c0 + 8] = *(short8*)&st[r][c0 + 8];
}

// ---------------------------------------------------------------------------
// wo transpose into the DEAD k/v columns of qkv (chunked layout).
// ---------------------------------------------------------------------------
__global__ __launch_bounds__(256) void wtrans_wo(
    const float* __restrict__ w, ushort* __restrict__ qkv)
{
    __shared__ ushort st[64][72];
    int n0 = blockIdx.x * 64, k0 = blockIdx.y * 64;
    int r  = threadIdx.x >> 2;
    int c0 = (threadIdx.x & 3) * 16;
    #pragma unroll
    for (int j = 0; j < 16; j += 4) {
        float4v f = *(const float4v*)&w[(size_t)(k0 + r) * DMODEL + n0 + c0 + j];
        st[c0 + j + 0][r] = f2bf(f[0]);
        st[c0 + j + 1][r] = f2bf(f[1]);
        st[c0 + j + 2][r] = f2bf(f[2]);
        st[c0 + j + 3][r] = f2bf(f[3]);
    }
    __syncthreads();
    ushort* dst = qkv + ((size_t)(2 * (n0 + r) + (k0 >> 10))) * NQKV + 2048 + (k0 & 1023);
    *(short8*)&dst[c0]     = *(short8*)&st[r][c0];
    *(short8*)&dst[c0 + 8] = *(short8*)&st[r][c0 + 8];
}

// ---------------------------------------------------------------------------
// Fused post-QKV: rope_q | ropek_cache | vtrans in one launch.
// ---------------------------------------------------------------------------
#define RQ_BLOCKS 14336
#define RK_BLOCKS 4096
__global__ __launch_bounds__(256) void postproc(
    ushort* __restrict__ qkv,
    const float* __restrict__ cosp, const float* __restrict__ sinp,
    float* __restrict__ kout, float* __restrict__ vout,
    ushort* __restrict__ kbf, ushort* __restrict__ vbfT)
{
    __shared__ ushort st[64][72];
    int bid = blockIdx.x;
    if (bid < RQ_BLOCKS) {
        int b   = bid / (RQ_BLOCKS / 2);
        int idx = (bid % (RQ_BLOCKS / 2)) * 256 + threadIdx.x;
        int i  = idx & 63;
        int h  = (idx >> 6) & 15;
        int tr = idx >> 10;
        int t  = NV + tr;
        size_t off = ((size_t)(b * TT + t)) * NQKV + h * DH + 2 * i;
        unsigned pk = *(const unsigned*)&qkv[off];
        float a  = bf2f((ushort)(pk & 0xffff));
        float bb = bf2f((ushort)(pk >> 16));
        float c  = cosp[tr * 64 + i];
        float s  = sinp[tr * 64 + i];
        *(unsigned*)&qkv[off] = cvtpk(a * c - bb * s, a * s + bb * c);
        return;
    }
    bid -= RQ_BLOCKS;
    if (bid < RK_BLOCKS) {
        int idx = bid * 256 + threadIdx.x;
        int i  = idx & 63;
        int kh = (idx >> 6) & 3;
        int t  = (idx >> 8) & 2047;
        int b  = idx >> 19;
        size_t row = ((size_t)(b * TT + t)) * NQKV;
        size_t dst = ((size_t)((b * NKV + kh) * TT + t)) * DH + 2 * i;
        unsigned pk = *(const unsigned*)&qkv[row + 2048 + kh * DH + 2 * i];
        float ka = bf2f((ushort)(pk & 0xffff));
        float kb = bf2f((ushort)(pk >> 16));
        if (t >= NV) {
            int pos = t - NV;
            float c = cosp[pos * 64 + i];
            float s = sinp[pos * 64 + i];
            float ra = ka * c - kb * s;
            float rb = ka * s + kb * c;
            ka = ra; kb = rb;
        }
        kout[dst]     = ka;
        kout[dst + 1] = kb;
        *(unsigned*)&kbf[dst] = cvtpk(ka, kb);
        unsigned pv = *(const unsigned*)&qkv[row + 2560 + kh * DH + 2 * i];
        vout[dst]     = bf2f((ushort)(pv & 0xffff));
        vout[dst + 1] = bf2f((ushort)(pv >> 16));
        return;
    }
    bid -= RK_BLOCKS;
    {
        int bx = bid & 31, by = (bid >> 5) & 1, bk = bid >> 6;
        int t0 = bx * 64, d0 = by * 64;
        int b = bk >> 2, kh = bk & 3;
        int r  = threadIdx.x >> 2;
        int c0 = (threadIdx.x & 3) * 16;
        const ushort* src = qkv + ((size_t)(b * TT + t0 + r)) * NQKV + 2560 + kh * DH + d0;
        short8 a0 = *(const short8*)&src[c0];
        short8 a1 = *(const short8*)&src[c0 + 8];
        #pragma unroll
        for (int j = 0; j < 8; j++) {
            st[c0 + j][r]     = (ushort)a0[j];
            st[c0 + 8 + j][r] = (ushort)a1[j];
        }
        __syncthreads();
        ushort* dst = vbfT + ((size_t)(bk * DH + d0 + r)) * TT + t0;
        *(short8*)&dst[c0]     = *(short8*)&st[r][c0];
        *(short8*)&dst[c0 + 8] = *(short8*)&st[r][c0 + 8];
    }
}

// ---------------------------------------------------------------------------
// GEMM (128x128, BK=32, XCD swizzle, 2-phase dbuf prefetch, standard sync).
// ---------------------------------------------------------------------------
__global__ __launch_bounds__(256) void gemm_lds(
    const ushort* __restrict__ A, int lda,
    const ushort* __restrict__ BT,
    ushort* __restrict__ C, int ldc, int K)
{
    __shared__ ushort As[2][128 * 32];
    __shared__ ushort Bs[2][128 * 32];

    int tid = threadIdx.x;
    int wave = tid >> 6, lane = tid & 63, quad = lane >> 4, l16 = lane & 15;

    int nwg = gridDim.x * gridDim.y;
    int bid = blockIdx.x + gridDim.x * blockIdx.y;
    int cpx = nwg >> 3;
    int swz = (bid & 7) * cpx + (bid >> 3);
    int bx = swz % gridDim.x, by = swz / gridDim.x;
    int m0 = by * 128, n0 = bx * 128;
    int wr = (wave >> 1) * 64, wc = (wave & 1) * 64;

    int srow = tid >> 2, scol = (tid & 3) * 8;
    const ushort* ag = A  + (size_t)(m0 + srow) * lda + scol;
    const ushort* bg = BT + (size_t)(n0 + srow) * K   + scol;
    int lo0 = (wave * 16) * 32;
    int lo1 = (64 + wave * 16) * 32;

    float4v acc[4][4];
    for (int i = 0; i < 4; i++)
        for (int j = 0; j < 4; j++)
            acc[i][j] = (float4v){0.f, 0.f, 0.f, 0.f};

    auto stage = [&](int buf, int k0) {
        GLDS16(ag + k0,                    As[buf] + lo0);
        GLDS16(ag + (size_t)64 * lda + k0, As[buf] + lo1);
        GLDS16(bg + k0,                    Bs[buf] + lo0);
        GLDS16(bg + (size_t)64 * K + k0,   Bs[buf] + lo1);
    };

    stage(0, 0);
    int it = 0;
    for (int k0 = 0; k0 < K; k0 += 32, ++it) {
        int cur = it & 1;
        __syncthreads();
        if (k0 + 32 < K) stage(cur ^ 1, k0 + 32);

        bf16x8 af[4], bfr[4];
        #pragma unroll
        for (int i = 0; i < 4; i++) af[i] = *(const bf16x8*)&As[cur][(wr + i * 16 + l16) * 32 + quad * 8];
        #pragma unroll
        for (int j = 0; j < 4; j++) bfr[j] = *(const bf16x8*)&Bs[cur][(wc + j * 16 + l16) * 32 + quad * 8];
        #pragma unroll
        for (int i = 0; i < 4; i++)
            #pragma unroll
            for (int j = 0; j < 4; j++)
                acc[i][j] = __builtin_amdgcn_mfma_f32_16x16x32_bf16(af[i], bfr[j], acc[i][j], 0, 0, 0);
    }

    #pragma unroll
    for (int i = 0; i < 4; i++)
        #pragma unroll
        for (int j = 0; j < 4; j++)
            #pragma unroll
            for (int r = 0; r < 4; r++) {
                int row = m0 + wr + i * 16 + quad * 4 + r;
                int col = n0 + wc + j * 16 + l16;
                C[(size_t)row * ldc + col] = f2bf(acc[i][j][r]);
            }
}

// ---------------------------------------------------------------------------
// Final projection GEMM (chunked-woT B operand).
// ---------------------------------------------------------------------------
__global__ __launch_bounds__(256) void gemm_out(
    const ushort* __restrict__ A,
    const ushort* __restrict__ Bc,
    float* __restrict__ C)
{
    __shared__ ushort As[2][128 * 32];
    __shared__ ushort Bs[2][128 * 32];

    int tid = threadIdx.x;
    int wave = tid >> 6, lane = tid & 63, quad = lane >> 4, l16 = lane & 15;

    int nwg = gridDim.x * gridDim.y;
    int bid = blockIdx.x + gridDim.x * blockIdx.y;
    int cpx = nwg >> 3;
    int swz = (bid & 7) * cpx + (bid >> 3);
    int bx = swz % gridDim.x, by = swz / gridDim.x;
    int m0 = by * 128, n0 = bx * 128;
    int wr = (wave >> 1) * 64, wc = (wave & 1) * 64;

    int srow = tid >> 2, scol = (tid & 3) * 8;
    const ushort* ag = A  + (size_t)(m0 + srow) * NQKV + scol;
    const ushort* bg = Bc + (size_t)(n0 + srow) * 6144 + scol;
    int lo0 = (wave * 16) * 32;
    int lo1 = (64 + wave * 16) * 32;

    float4v acc[4][4];
    for (int i = 0; i < 4; i++)
        for (int j = 0; j < 4; j++)
            acc[i][j] = (float4v){0.f, 0.f, 0.f, 0.f};

    auto stage = [&](int buf, int k0) {
        int koff = ((k0 >> 10) * NQKV) + (k0 & 1023);
        GLDS16(ag + k0,                       As[buf] + lo0);
        GLDS16(ag + (size_t)64 * NQKV + k0,   As[buf] + lo1);
        GLDS16(bg + koff,                     Bs[buf] + lo0);
        GLDS16(bg + (size_t)64 * 6144 + koff, Bs[buf] + lo1);
    };

    stage(0, 0);
    int it = 0;
    for (int k0 = 0; k0 < 2048; k0 += 32, ++it) {
        int cur = it & 1;
        __syncthreads();
        if (k0 + 32 < 2048) stage(cur ^ 1, k0 + 32);

        bf16x8 af[4], bfr[4];
        #pragma unroll
        for (int i = 0; i < 4; i++) af[i] = *(const bf16x8*)&As[cur][(wr + i * 16 + l16) * 32 + quad * 8];
        #pragma unroll
        for (int j = 0; j < 4; j++) bfr[j] = *(const bf16x8*)&Bs[cur][(wc + j * 16 + l16) * 32 + quad * 8];
        #pragma unroll
        for (int i = 0; i < 4; i++)
            #pragma unroll
            for (int j = 0; j < 4; j++)
                acc[i][j] = __builtin_amdgcn_mfma_f32_16x16x32_bf16(af[i], bfr[j], acc[i][j], 0, 0, 0);
    }

    #pragma unroll
    for (int i = 0; i < 4; i++)
        #pragma unroll
        for (int j = 0; j < 4; j++)
            #pragma unroll
            for (int r = 0; r < 4; r++) {
                int row = m0 + wr + i * 16 + quad * 4 + r;
                int col = n0 + wc + j * 16 + l16;
                C[(size_t)row * DMODEL + col] = acc[i][j][r];
            }
}

// ---------------------------------------------------------------------------
// Flash attention, 2 q-heads/block, job-table split-KV (r7-verified).
// r8: P handoff to PV via per-wave LDS tile (granule-XOR-swizzled) instead of
// 32 ds_bpermute + 32 cndmask per tile. P region is WAVE-PRIVATE: producer
// and consumer are the same wave; DS ops execute in order per wave -> no new
// barriers. LDS 80 KB (2 blocks/CU x 80 = 160 KB exactly).
// P layout per wave per head: [q=16][granule g=k>>3, XOR q&7][k&7] bf16.
// ---------------------------------------------------------------------------
__global__ __launch_bounds__(256, 2) void attn_kernel(
    ushort* qkv,
    const ushort* __restrict__ kbf, const ushort* __restrict__ vbfT,
    ushort* __restrict__ pO, float* __restrict__ ml)
{
    __shared__ ushort shm[40960];   // 80 KB: 2x(K 16KB+V 16KB) + 4 waves x 4KB P

    int tid = threadIdx.x;
    int wave = tid >> 6, lane = tid & 63, quad = lane >> 4, l16 = lane & 15;
    int hy = blockIdx.x;                  // head-pair 0..7 (fastest -> XCD pin)
    int job = blockIdx.y;
    int b  = blockIdx.z;
    int qt  = J_QT[job];
    int kt0 = J_K0[job];
    int kt1 = J_K1[job];
    int ph  = J_PH[job];
    int h0 = hy * 2;
    int kh = hy >> 1;
    int q0 = qt * 64;

    int srow = tid >> 2, scol = (tid & 3) * 8;

    ushort* qbase0 = qkv + ((size_t)(b * TT) + q0) * NQKV + h0 * DH;
    ushort* qbase1 = qbase0 + DH;
    #pragma unroll
    for (int dk = 0; dk < 4; dk++) {
        GLDS16(qbase0 + (size_t)srow * NQKV + dk * 32 + scol, shm + dk * 2048 + wave * 512);
        GLDS16(qbase1 + (size_t)srow * NQKV + dk * 32 + scol, shm + 16384 + dk * 2048 + wave * 512);
    }
    __syncthreads();
    bf16x8 qf0[4], qf1[4];
    #pragma unroll
    for (int dk = 0; dk < 4; dk++) {
        qf0[dk] = *(const bf16x8*)&shm[dk * 2048 + (wave * 16 + l16) * 32 + quad * 8];
        qf1[dk] = *(const bf16x8*)&shm[16384 + dk * 2048 + (wave * 16 + l16) * 32 + quad * 8];
    }
    __syncthreads();

    float4v O0[8], O1[8];
    #pragma unroll
    for (int i = 0; i < 8; i++) {
        O0[i] = (float4v){0.f, 0.f, 0.f, 0.f};
        O1[i] = (float4v){0.f, 0.f, 0.f, 0.f};
    }
    float m0r = -1e30f, l0r = 0.f;
    float m1r = -1e30f, l1r = 0.f;

    const float scale = 0.08838834764831845f;   // 1/sqrt(128)
    const float THRR  = 90.50966799f;           // 8/scale
    int qg = q0 + wave * 16 + l16;

    const ushort* kb2 = kbf  + ((size_t)(b * NKV + kh)) * TT * DH;
    const ushort* vb2 = vbfT + ((size_t)(b * NKV + kh)) * DH * TT;

    // per-wave P buffer (wave-private; no cross-wave sync needed)
    ushort* Pl = shm + 32768 + wave * 2048;     // [head 2][q 16][k 64] bf16
    int qsw = l16 & 7;

    auto stage = [&](int buf, int kt) {
        ushort* Kb = shm + buf * 16384;
        ushort* Vb = Kb + 8192;
        int k0 = kt * 64;
        #pragma unroll
        for (int dk = 0; dk < 4; dk++)
            GLDS16(kb2 + (size_t)(k0 + srow) * DH + dk * 32 + scol, Kb + dk * 2048 + wave * 512);
        #pragma unroll
        for (int kk = 0; kk < 2; kk++)
            #pragma unroll
            for (int p = 0; p < 2; p++)
                GLDS16(vb2 + (size_t)(p * 64 + srow) * TT + k0 + kk * 32 + scol,
                       Vb + kk * 4096 + (p * 64 + wave * 16) * 32);
    };

    stage(0, kt0);

    for (int kt = kt0; kt < kt1; kt++) {
        int cur = (kt - kt0) & 1;
        __syncthreads();
        if (kt + 1 < kt1)
            stage(cur ^ 1, kt + 1);

        const ushort* Kc = shm + cur * 16384;
        const ushort* Vc = Kc + 8192;
        int k0 = kt * 64;

        float4v s0[4], s1[4];
        __builtin_amdgcn_s_setprio(1);
        #pragma unroll
        for (int t2i = 0; t2i < 4; t2i++) {
            float4v a0 = (float4v){0.f, 0.f, 0.f, 0.f};
            float4v a1 = (float4v){0.f, 0.f, 0.f, 0.f};
            #pragma unroll
            for (int dk = 0; dk < 4; dk++) {
                bf16x8 af = *(const bf16x8*)&Kc[dk * 2048 + (t2i * 16 + l16) * 32 + quad * 8];
                a0 = __builtin_amdgcn_mfma_f32_16x16x32_bf16(af, qf0[dk], a0, 0, 0, 0);
                a1 = __builtin_amdgcn_mfma_f32_16x16x32_bf16(af, qf1[dk], a1, 0, 0, 0);
            }
            s0[t2i] = a0; s1[t2i] = a1;
        }
        __builtin_amdgcn_s_setprio(0);

        if ((q0 >= NV) && (kt == qt)) {
            #pragma unroll
            for (int t2i = 0; t2i < 4; t2i++)
                #pragma unroll
                for (int i = 0; i < 4; i++)
                    if (k0 + t2i * 16 + quad * 4 + i > qg) {
                        s0[t2i][i] = -1e9f;
                        s1[t2i][i] = -1e9f;
                    }
        }

        float mx0 = -1e30f, mx1 = -1e30f;
        #pragma unroll
        for (int t2i = 0; t2i < 4; t2i++)
            #pragma unroll
            for (int i = 0; i < 4; i++) {
                mx0 = fmaxf(mx0, s0[t2i][i]);
                mx1 = fmaxf(mx1, s1[t2i][i]);
            }
        mx0 = fmaxf(mx0, __shfl_xor(mx0, 16, 64));
        mx0 = fmaxf(mx0, __shfl_xor(mx0, 32, 64));
        mx1 = fmaxf(mx1, __shfl_xor(mx1, 16, 64));
        mx1 = fmaxf(mx1, __shfl_xor(mx1, 32, 64));

        bool skip0 = __all(mx0 <= m0r + THRR);
        bool skip1 = __all(mx1 <= m1r + THRR);
        float mn0 = fmaxf(m0r, mx0), mn1 = fmaxf(m1r, mx1);
        float mref0 = skip0 ? m0r : mn0;
        float mref1 = skip1 ? m1r : mn1;
        float nb0 = -mref0 * scale;
        float nb1 = -mref1 * scale;

        float ss0 = 0.f, ss1 = 0.f;
        #pragma unroll
        for (int t2i = 0; t2i < 4; t2i++)
            #pragma unroll
            for (int i = 0; i < 4; i++) {
                float p0 = __expf(__builtin_fmaf(s0[t2i][i], scale, nb0)); s0[t2i][i] = p0; ss0 += p0;
                float p1 = __expf(__builtin_fmaf(s1[t2i][i], scale, nb1)); s1[t2i][i] = p1; ss1 += p1;
            }
        ss0 += __shfl_xor(ss0, 16, 64); ss0 += __shfl_xor(ss0, 32, 64);
        ss1 += __shfl_xor(ss1, 16, 64); ss1 += __shfl_xor(ss1, 32, 64);

        if (!skip0) {
            float al0 = __expf((m0r - mn0) * scale);
            #pragma unroll
            for (int dt = 0; dt < 8; dt++)
                #pragma unroll
                for (int i = 0; i < 4; i++) O0[dt][i] *= al0;
            l0r *= al0;
            m0r = mn0;
        }
        l0r += ss0;
        if (!skip1) {
            float al1 = __expf((m1r - mn1) * scale);
            #pragma unroll
            for (int dt = 0; dt < 8; dt++)
                #pragma unroll
                for (int i = 0; i < 4; i++) O1[dt][i] *= al1;
            l1r *= al1;
            m1r = mn1;
        }
        l1r += ss1;

        // ---- P -> per-wave LDS (producer: lane holds P[t2i*16+quad*4+i][q=l16])
        // granule g = k>>3 = t2i*2 + (quad>>1); within-granule off = (quad&1)*4 + i
        #pragma unroll
        for (int t2i = 0; t2i < 4; t2i++) {
            int g = t2i * 2 + (quad >> 1);
            int base = l16 * 64 + ((g ^ qsw) << 3) + (quad & 1) * 4;
            *(unsigned*)&Pl[base]            = cvtpk(s0[t2i][0], s0[t2i][1]);
            *(unsigned*)&Pl[base + 2]        = cvtpk(s0[t2i][2], s0[t2i][3]);
            *(unsigned*)&Pl[1024 + base]     = cvtpk(s1[t2i][0], s1[t2i][1]);
            *(unsigned*)&Pl[1024 + base + 2] = cvtpk(s1[t2i][2], s1[t2i][3]);
        }

        // ---- PV: B-fragment = P[k = kk*32+quad*8+j][q=l16] as one b128 read
        #pragma unroll
        for (int kk = 0; kk < 2; kk++) {
            int gc = kk * 4 + quad;
            int raddr = l16 * 64 + ((gc ^ qsw) << 3);
            bf16x8 pf0 = *(const bf16x8*)&Pl[raddr];
            bf16x8 pf1 = *(const bf16x8*)&Pl[1024 + raddr];
            __builtin_amdgcn_s_setprio(1);
            #pragma unroll
            for (int dt = 0; dt < 8; dt++) {
                bf16x8 vf = *(const bf16x8*)&Vc[kk * 4096 + (dt * 16 + l16) * 32 + quad * 8];
                O0[dt] = __builtin_amdgcn_mfma_f32_16x16x32_bf16(vf, pf0, O0[dt], 0, 0, 0);
                O1[dt] = __builtin_amdgcn_mfma_f32_16x16x32_bf16(vf, pf1, O1[dt], 0, 0, 0);
            }
            __builtin_amdgcn_s_setprio(0);
        }
    }

    // epilogue: normalized O; whole jobs + half1 -> qkv, half0 -> scratch.
    float rinv0 = 1.f / l0r, rinv1 = 1.f / l1r;
    int qrow = wave * 16 + l16;
    if (ph == 255 || (ph & 1)) {
        size_t orow = (size_t)qrow * NQKV;
        #pragma unroll
        for (int dt = 0; dt < 8; dt++)
            #pragma unroll
            for (int i = 0; i < 4; i += 2) {
                unsigned pk0 = cvtpk(O0[dt][i] * rinv0, O0[dt][i + 1] * rinv0);
                unsigned pk1 = cvtpk(O1[dt][i] * rinv1, O1[dt][i + 1] * rinv1);
                *(unsigned*)&qbase0[orow + dt * 16 + quad * 4 + i] = pk0;
                *(unsigned*)&qbase1[orow + dt * 16 + quad * 4 + i] = pk1;
            }
    } else {
        int g = ((b * 8 + hy) * NSLOT) + (ph >> 1);
        ushort* pb = pO + (size_t)g * 16384 + qrow * 256;
        #pragma unroll
        for (int dt = 0; dt < 8; dt++)
            #pragma unroll
            for (int i = 0; i < 4; i += 2) {
                int d = dt * 16 + quad * 4 + i;
                *(unsigned*)&pb[d]       = cvtpk(O0[dt][i] * rinv0, O0[dt][i + 1] * rinv0);
                *(unsigned*)&pb[128 + d] = cvtpk(O1[dt][i] * rinv1, O1[dt][i + 1] * rinv1);
            }
    }
    if (ph != 255 && quad == 0) {
        int g = ((b * 8 + hy) * NSLOT) + (ph >> 1);
        int half = ph & 1;
        float* mlb = ml + (size_t)g * 512 + half * 256 + qrow * 2;
        mlb[0]   = m0r;  mlb[1]   = l0r;    // head 0
        mlb[128] = m1r;  mlb[129] = l1r;    // head 1
    }
}

// ---------------------------------------------------------------------------
// Combine split-KV halves: qkv = (w0*P0 + w1*P1), wi = e^{(mi-m)s}*li / Z.
// ---------------------------------------------------------------------------
__global__ __launch_bounds__(256) void combine_split(
    ushort* __restrict__ qkv, const ushort* __restrict__ pO,
    const float* __restrict__ ml)
{
    int g = blockIdx.x;
    int slice = g / NSLOT, local = g % NSLOT;
    int b = slice >> 3, hy = slice & 7;
    int qt = (local < 4) ? local : (13 + local);
    int h0 = hy * 2;
    int q0 = qt * 64;

    int t = threadIdx.x;
    int r = t >> 2, seg = t & 3;
    int head = seg >> 1;
    const float scale = 0.08838834764831845f;

    const float* mlg = ml + (size_t)g * 512;
    float m0 = mlg[0 * 256 + head * 128 + r * 2];
    float l0 = mlg[0 * 256 + head * 128 + r * 2 + 1];
    float m1 = mlg[1 * 256 + head * 128 + r * 2];
    float l1 = mlg[1 * 256 + head * 128 + r * 2 + 1];
    float mm = fmaxf(m0, m1);
    float w0 = __expf((m0 - mm) * scale) * l0;
    float w1 = __expf((m1 - mm) * scale) * l1;
    float inv = 1.f / (w0 + w1);
    float a0 = w0 * inv, a1 = w1 * inv;

    const ushort* p = pO + (size_t)g * 16384 + r * 256 + seg * 64;
    ushort* q = qkv + ((size_t)(b * TT + q0 + r)) * NQKV + (h0 + head) * DH + (seg & 1) * 64;

    #pragma unroll
    for (int j = 0; j < 64; j += 2) {
        unsigned u0 = *(const unsigned*)&p[j];
        unsigned u1 = *(const unsigned*)&q[j];
        float lo = bf2f((ushort)(u0 & 0xffff)) * a0 + bf2f((ushort)(u1 & 0xffff)) * a1;
        float hi2 = bf2f((ushort)(u0 >> 16)) * a0 + bf2f((ushort)(u1 >> 16)) * a1;
        *(unsigned*)&q[j] = cvtpk(lo, hi2);
    }
}

// ---------------------------------------------------------------------------
extern "C" void kernel_launch(void* const* d_in, const int* in_sizes, int n_in,
                              void* d_out, int out_size, void* d_ws, size_t ws_size,
                              hipStream_t stream) {
    const float* x    = (const float*)d_in[0];
    const float* cosp = (const float*)d_in[1];
    const float* sinp = (const float*)d_in[2];
    const float* wq   = (const float*)d_in[3];
    const float* wk   = (const float*)d_in[4];
    const float* wv   = (const float*)d_in[5];
    const float* wo   = (const float*)d_in[6];

    float* out  = (float*)d_out;                         // (B,T,DMODEL) f32
    float* kout = out + (size_t)BB * TT * DMODEL;        // (B,NKV,T,DH) f32
    float* vout = kout + (size_t)BB * NKV * TT * DH;

    ushort* sc    = (ushort*)d_out;
    ushort* wqkvT = sc;                                   // [3072][2048] bf16
    ushort* xbf   = sc + (size_t)NQKV * DMODEL;           // [4096][2048] bf16
    ushort* kbf   = sc + (size_t)NQKV * DMODEL;           // (B,NKV,T,DH) bf16
    ushort* vbfT  = kbf + (size_t)BB * NKV * TT * DH;     // (B,NKV,DH,T) bf16
    ushort* pO    = sc;                                   // aliases dead wqkvT
    float*  ml    = (float*)(sc + 15000000);              // dead xbf tail zone

    ushort* qkv = (ushort*)d_ws;

    const int M = BB * TT;  // 4096

    convert_x<<<dim3((size_t)M * DMODEL / 2048), 256, 0, stream>>>(x, xbf);
    wtrans_all<<<dim3(NQKV / 64, DMODEL / 64), 256, 0, stream>>>(wq, wk, wv, wqkvT);

    gemm_lds<<<dim3(NQKV / 128, M / 128), 256, 0, stream>>>(
        xbf, DMODEL, wqkvT, qkv, NQKV, DMODEL);

    postproc<<<dim3(RQ_BLOCKS + RK_BLOCKS + 512), 256, 0, stream>>>(
        qkv, cosp, sinp, kout, vout, kbf, vbfT);

    wtrans_wo<<<dim3(DMODEL / 64, DMODEL / 64), 256, 0, stream>>>(wo, qkv);

    attn_kernel<<<dim3(NH / 2, NJOB, BB), 256, 0, stream>>>(qkv, kbf, vbfT, pO, ml);

    combine_split<<<dim3(16 * NSLOT), 256, 0, stream>>>(qkv, pO, ml);

    gemm_out<<<dim3(DMODEL / 128, M / 128), 256, 0, stream>>>(qkv, qkv + 2048, out);
}

// Round 9
// 342.690 us; speedup vs baseline: 1.0312x; 1.0312x over previous
//
#include <hip/hip_runtime.h>
#include <hip/hip_bf16.h>

#define BB 2
#define TT 2048
#define DMODEL 2048
#define NH 16
#define NKV 4
#define DH 128
#define NV 256
#define TL (TT - NV)   // 1792
#define NQKV 3072      // fused projection width: q 2048 | k 512 | v 512

typedef __bf16  bf16x8  __attribute__((ext_vector_type(8)));
typedef float   float4v __attribute__((ext_vector_type(4)));
typedef short   short8  __attribute__((ext_vector_type(8)));
typedef unsigned short ushort;

__device__ __forceinline__ float bf2f(ushort u) {
    union { float f; unsigned i; } c; c.i = ((unsigned)u) << 16; return c.f;
}
__device__ __forceinline__ ushort f2bf(float f) {
    union { float f; unsigned i; } c; c.f = f;
    unsigned r = c.i + 0x7fff + ((c.i >> 16) & 1);
    return (ushort)(r >> 16);
}
// pack two f32 -> 2x bf16 in one instr (low = a, high = b), RNE
__device__ __forceinline__ unsigned cvtpk(float a, float b) {
    unsigned r;
    asm("v_cvt_pk_bf16_f32 %0, %1, %2" : "=v"(r) : "v"(a), "v"(b));
    return r;
}

// async global->LDS, 16B per lane; LDS dest = wave-uniform base + lane*16
#define GLDS16(g, l) __builtin_amdgcn_global_load_lds( \
    (__attribute__((address_space(1))) void*)(g), \
    (__attribute__((address_space(3))) void*)(l), 16, 0, 0)

// ---------------------------------------------------------------------------
// attn job table: 51 jobs per (head-pair, batch) slice, LPT-ordered.
// Split q-tiles (nkt>=18): vision 0..3 and text 17..31 -> two KV halves.
// J_PH: 255 = whole job; else pslot_local*2 + half (half0 -> scratch partial).
// ---------------------------------------------------------------------------
#define NJOB 51
#define NSLOT 19
#define WOJOBS 64   // extra z-slots carrying wtrans_wo tiles (64*16 = 1024)
__device__ const short J_QT[NJOB] = {
    16,  0, 0, 1, 1, 2, 2, 3, 3, 31, 31, 30, 15,
    30, 29, 29, 28, 14, 28, 27, 27, 26, 13, 26, 25, 25, 24, 12,
    24, 23, 23, 22, 11, 22, 21, 21, 20, 10, 20, 19, 19, 18,  9,
    18, 17, 17,  8,  7,  6,  5,  4 };
__device__ const short J_K0[NJOB] = {
     0,  0,16, 0,16, 0,16, 0,16,  0, 16,  0,  0,
    16,  0,15, 0,  0, 15,  0, 14,  0,  0, 14,  0, 13,  0,  0,
    13,  0,12, 0,  0, 12,  0, 11,  0,  0, 11,  0, 10,  0,  0,
    10,  0, 9, 0,  0,  0,  0,  0 };
__device__ const short J_K1[NJOB] = {
    17, 16,32,16,32,16,32,16,32, 16, 32, 16, 16,
    31, 15,30,15, 15, 29, 14, 28, 14, 14, 27, 13, 26, 13, 13,
    25, 12,24,12, 12, 23, 11, 22, 11, 11, 21, 10, 20, 10, 10,
    19,  9,18, 9,  8,  7,  6,  5 };
__device__ const short J_PH[NJOB] = {
   255,  0, 1, 2, 3, 4, 5, 6, 7, 36, 37, 34,255,
    35, 32,33,30,255, 31, 28, 29, 26,255, 27, 24, 25, 22,255,
    23, 20,21,18,255, 19, 16, 17, 14,255, 15, 12, 13, 10,255,
    11,  8, 9,255,255,255,255,255 };

// ---------------------------------------------------------------------------
// prep: convert_x (blocks [0,4096)) | wtrans_all (blocks [4096,5632)).
// ---------------------------------------------------------------------------
__global__ __launch_bounds__(256) void prep(
    const float* __restrict__ x, ushort* __restrict__ xbf,
    const float* __restrict__ wq, const float* __restrict__ wk,
    const float* __restrict__ wv, ushort* __restrict__ wT)
{
    __shared__ ushort st[64][72];
    int bid = blockIdx.x;
    if (bid < 4096) {
        // ---- convert_x: x f32 -> bf16, 8 elems/thread ----
        size_t i = ((size_t)bid * 256 + threadIdx.x) * 8;
        float4v f0 = *(const float4v*)&x[i];
        float4v f1 = *(const float4v*)&x[i + 4];
        short8 h;
        h[0] = (short)f2bf(f0[0]); h[1] = (short)f2bf(f0[1]);
        h[2] = (short)f2bf(f0[2]); h[3] = (short)f2bf(f0[3]);
        h[4] = (short)f2bf(f1[0]); h[5] = (short)f2bf(f1[1]);
        h[6] = (short)f2bf(f1[2]); h[7] = (short)f2bf(f1[3]);
        *(short8*)&xbf[i] = h;
        return;
    }
    // ---- wtrans_all: wq|wk|wv -> wqkvT[3072][2048] bf16, 64x64 tiles ----
    bid -= 4096;                       // [0,1536)
    int bx = bid % 48, by = bid / 48;
    int n0 = bx * 64, k0 = by * 64;
    const float* w; int N, nn;
    if (n0 < 2048)      { w = wq; N = 2048; nn = n0; }
    else if (n0 < 2560) { w = wk; N = 512;  nn = n0 - 2048; }
    else                { w = wv; N = 512;  nn = n0 - 2560; }
    int r  = threadIdx.x >> 2;
    int c0 = (threadIdx.x & 3) * 16;
    #pragma unroll
    for (int j = 0; j < 16; j += 4) {
        float4v f = *(const float4v*)&w[(size_t)(k0 + r) * N + nn + c0 + j];
        st[c0 + j + 0][r] = f2bf(f[0]);
        st[c0 + j + 1][r] = f2bf(f[1]);
        st[c0 + j + 2][r] = f2bf(f[2]);
        st[c0 + j + 3][r] = f2bf(f[3]);
    }
    __syncthreads();
    ushort* dst = &wT[(size_t)(n0 + r) * DMODEL + k0];
    *(short8*)&dst[c0]     = *(short8*)&st[r][c0];
    *(short8*)&dst[c0 + 8] = *(short8*)&st[r][c0 + 8];
}

// ---------------------------------------------------------------------------
// Fused post-QKV: rope_q | ropek_cache | vtrans in one launch.
// ---------------------------------------------------------------------------
#define RQ_BLOCKS 14336
#define RK_BLOCKS 4096
__global__ __launch_bounds__(256) void postproc(
    ushort* __restrict__ qkv,
    const float* __restrict__ cosp, const float* __restrict__ sinp,
    float* __restrict__ kout, float* __restrict__ vout,
    ushort* __restrict__ kbf, ushort* __restrict__ vbfT)
{
    __shared__ ushort st[64][72];
    int bid = blockIdx.x;
    if (bid < RQ_BLOCKS) {
        int b   = bid / (RQ_BLOCKS / 2);
        int idx = (bid % (RQ_BLOCKS / 2)) * 256 + threadIdx.x;
        int i  = idx & 63;
        int h  = (idx >> 6) & 15;
        int tr = idx >> 10;
        int t  = NV + tr;
        size_t off = ((size_t)(b * TT + t)) * NQKV + h * DH + 2 * i;
        unsigned pk = *(const unsigned*)&qkv[off];
        float a  = bf2f((ushort)(pk & 0xffff));
        float bb = bf2f((ushort)(pk >> 16));
        float c  = cosp[tr * 64 + i];
        float s  = sinp[tr * 64 + i];
        *(unsigned*)&qkv[off] = cvtpk(a * c - bb * s, a * s + bb * c);
        return;
    }
    bid -= RQ_BLOCKS;
    if (bid < RK_BLOCKS) {
        int idx = bid * 256 + threadIdx.x;
        int i  = idx & 63;
        int kh = (idx >> 6) & 3;
        int t  = (idx >> 8) & 2047;
        int b  = idx >> 19;
        size_t row = ((size_t)(b * TT + t)) * NQKV;
        size_t dst = ((size_t)((b * NKV + kh) * TT + t)) * DH + 2 * i;
        unsigned pk = *(const unsigned*)&qkv[row + 2048 + kh * DH + 2 * i];
        float ka = bf2f((ushort)(pk & 0xffff));
        float kb = bf2f((ushort)(pk >> 16));
        if (t >= NV) {
            int pos = t - NV;
            float c = cosp[pos * 64 + i];
            float s = sinp[pos * 64 + i];
            float ra = ka * c - kb * s;
            float rb = ka * s + kb * c;
            ka = ra; kb = rb;
        }
        kout[dst]     = ka;
        kout[dst + 1] = kb;
        *(unsigned*)&kbf[dst] = cvtpk(ka, kb);
        unsigned pv = *(const unsigned*)&qkv[row + 2560 + kh * DH + 2 * i];
        vout[dst]     = bf2f((ushort)(pv & 0xffff));
        vout[dst + 1] = bf2f((ushort)(pv >> 16));
        return;
    }
    bid -= RK_BLOCKS;
    {
        int bx = bid & 31, by = (bid >> 5) & 1, bk = bid >> 6;
        int t0 = bx * 64, d0 = by * 64;
        int b = bk >> 2, kh = bk & 3;
        int r  = threadIdx.x >> 2;
        int c0 = (threadIdx.x & 3) * 16;
        const ushort* src = qkv + ((size_t)(b * TT + t0 + r)) * NQKV + 2560 + kh * DH + d0;
        short8 a0 = *(const short8*)&src[c0];
        short8 a1 = *(const short8*)&src[c0 + 8];
        #pragma unroll
        for (int j = 0; j < 8; j++) {
            st[c0 + j][r]     = (ushort)a0[j];
            st[c0 + 8 + j][r] = (ushort)a1[j];
        }
        __syncthreads();
        ushort* dst = vbfT + ((size_t)(bk * DH + d0 + r)) * TT + t0;
        *(short8*)&dst[c0]     = *(short8*)&st[r][c0];
        *(short8*)&dst[c0 + 8] = *(short8*)&st[r][c0 + 8];
    }
}

// ---------------------------------------------------------------------------
// GEMM (128x128, BK=32, XCD swizzle, 2-phase dbuf prefetch, standard sync).
// ---------------------------------------------------------------------------
__global__ __launch_bounds__(256) void gemm_lds(
    const ushort* __restrict__ A, int lda,
    const ushort* __restrict__ BT,
    ushort* __restrict__ C, int ldc, int K)
{
    __shared__ ushort As[2][128 * 32];
    __shared__ ushort Bs[2][128 * 32];

    int tid = threadIdx.x;
    int wave = tid >> 6, lane = tid & 63, quad = lane >> 4, l16 = lane & 15;

    int nwg = gridDim.x * gridDim.y;
    int bid = blockIdx.x + gridDim.x * blockIdx.y;
    int cpx = nwg >> 3;
    int swz = (bid & 7) * cpx + (bid >> 3);
    int bx = swz % gridDim.x, by = swz / gridDim.x;
    int m0 = by * 128, n0 = bx * 128;
    int wr = (wave >> 1) * 64, wc = (wave & 1) * 64;

    int srow = tid >> 2, scol = (tid & 3) * 8;
    const ushort* ag = A  + (size_t)(m0 + srow) * lda + scol;
    const ushort* bg = BT + (size_t)(n0 + srow) * K   + scol;
    int lo0 = (wave * 16) * 32;
    int lo1 = (64 + wave * 16) * 32;

    float4v acc[4][4];
    for (int i = 0; i < 4; i++)
        for (int j = 0; j < 4; j++)
            acc[i][j] = (float4v){0.f, 0.f, 0.f, 0.f};

    auto stage = [&](int buf, int k0) {
        GLDS16(ag + k0,                    As[buf] + lo0);
        GLDS16(ag + (size_t)64 * lda + k0, As[buf] + lo1);
        GLDS16(bg + k0,                    Bs[buf] + lo0);
        GLDS16(bg + (size_t)64 * K + k0,   Bs[buf] + lo1);
    };

    stage(0, 0);
    int it = 0;
    for (int k0 = 0; k0 < K; k0 += 32, ++it) {
        int cur = it & 1;
        __syncthreads();
        if (k0 + 32 < K) stage(cur ^ 1, k0 + 32);

        bf16x8 af[4], bfr[4];
        #pragma unroll
        for (int i = 0; i < 4; i++) af[i] = *(const bf16x8*)&As[cur][(wr + i * 16 + l16) * 32 + quad * 8];
        #pragma unroll
        for (int j = 0; j < 4; j++) bfr[j] = *(const bf16x8*)&Bs[cur][(wc + j * 16 + l16) * 32 + quad * 8];
        #pragma unroll
        for (int i = 0; i < 4; i++)
            #pragma unroll
            for (int j = 0; j < 4; j++)
                acc[i][j] = __builtin_amdgcn_mfma_f32_16x16x32_bf16(af[i], bfr[j], acc[i][j], 0, 0, 0);
    }

    #pragma unroll
    for (int i = 0; i < 4; i++)
        #pragma unroll
        for (int j = 0; j < 4; j++)
            #pragma unroll
            for (int r = 0; r < 4; r++) {
                int row = m0 + wr + i * 16 + quad * 4 + r;
                int col = n0 + wc + j * 16 + l16;
                C[(size_t)row * ldc + col] = f2bf(acc[i][j][r]);
            }
}

// ---------------------------------------------------------------------------
// Final projection GEMM (chunked-woT B operand).
// ---------------------------------------------------------------------------
__global__ __launch_bounds__(256) void gemm_out(
    const ushort* __restrict__ A,
    const ushort* __restrict__ Bc,
    float* __restrict__ C)
{
    __shared__ ushort As[2][128 * 32];
    __shared__ ushort Bs[2][128 * 32];

    int tid = threadIdx.x;
    int wave = tid >> 6, lane = tid & 63, quad = lane >> 4, l16 = lane & 15;

    int nwg = gridDim.x * gridDim.y;
    int bid = blockIdx.x + gridDim.x * blockIdx.y;
    int cpx = nwg >> 3;
    int swz = (bid & 7) * cpx + (bid >> 3);
    int bx = swz % gridDim.x, by = swz / gridDim.x;
    int m0 = by * 128, n0 = bx * 128;
    int wr = (wave >> 1) * 64, wc = (wave & 1) * 64;

    int srow = tid >> 2, scol = (tid & 3) * 8;
    const ushort* ag = A  + (size_t)(m0 + srow) * NQKV + scol;
    const ushort* bg = Bc + (size_t)(n0 + srow) * 6144 + scol;
    int lo0 = (wave * 16) * 32;
    int lo1 = (64 + wave * 16) * 32;

    float4v acc[4][4];
    for (int i = 0; i < 4; i++)
        for (int j = 0; j < 4; j++)
            acc[i][j] = (float4v){0.f, 0.f, 0.f, 0.f};

    auto stage = [&](int buf, int k0) {
        int koff = ((k0 >> 10) * NQKV) + (k0 & 1023);
        GLDS16(ag + k0,                       As[buf] + lo0);
        GLDS16(ag + (size_t)64 * NQKV + k0,   As[buf] + lo1);
        GLDS16(bg + koff,                     Bs[buf] + lo0);
        GLDS16(bg + (size_t)64 * 6144 + koff, Bs[buf] + lo1);
    };

    stage(0, 0);
    int it = 0;
    for (int k0 = 0; k0 < 2048; k0 += 32, ++it) {
        int cur = it & 1;
        __syncthreads();
        if (k0 + 32 < 2048) stage(cur ^ 1, k0 + 32);

        bf16x8 af[4], bfr[4];
        #pragma unroll
        for (int i = 0; i < 4; i++) af[i] = *(const bf16x8*)&As[cur][(wr + i * 16 + l16) * 32 + quad * 8];
        #pragma unroll
        for (int j = 0; j < 4; j++) bfr[j] = *(const bf16x8*)&Bs[cur][(wc + j * 16 + l16) * 32 + quad * 8];
        #pragma unroll
        for (int i = 0; i < 4; i++)
            #pragma unroll
            for (int j = 0; j < 4; j++)
                acc[i][j] = __builtin_amdgcn_mfma_f32_16x16x32_bf16(af[i], bfr[j], acc[i][j], 0, 0, 0);
    }

    #pragma unroll
    for (int i = 0; i < 4; i++)
        #pragma unroll
        for (int j = 0; j < 4; j++)
            #pragma unroll
            for (int r = 0; r < 4; r++) {
                int row = m0 + wr + i * 16 + quad * 4 + r;
                int col = n0 + wc + j * 16 + l16;
                C[(size_t)row * DMODEL + col] = acc[i][j][r];
            }
}

// ---------------------------------------------------------------------------
// Flash attention, 2 q-heads/block, job-table split-KV (r7/r8-verified) +
// r9: grid (8 hy, 2 b, NJOB+64 z) — z slowest so jobs are globally
// LPT-ordered across batches; z >= NJOB blocks do wtrans_wo tiles (disjoint
// address set: wo -> qkv kv-cols; attn touches only q-cols + scratch), and
// backfill tail-idle CUs. Standard sync only.
// ---------------------------------------------------------------------------
__global__ __launch_bounds__(256, 2) void attn_kernel(
    ushort* qkv,
    const ushort* __restrict__ kbf, const ushort* __restrict__ vbfT,
    ushort* __restrict__ pO, float* __restrict__ ml,
    const float* __restrict__ wo)
{
    __shared__ ushort shm[40960];   // 80 KB: 2x(K 16KB+V 16KB) + 4 waves x 4KB P

    int tid = threadIdx.x;
    int hy = blockIdx.x;                  // head-pair 0..7 (fastest -> XCD pin)
    int b  = blockIdx.y;
    int zz = blockIdx.z;

    if (zz >= NJOB) {
        // ---- wtrans_wo tile: wo[K][N] f32 -> chunked woT in qkv kv-cols ----
        int idx = (zz - NJOB) * 16 + b * 8 + hy;    // 0..1023
        int n0 = (idx & 31) * 64, k0 = (idx >> 5) * 64;
        ushort (*st)[72] = (ushort(*)[72])shm;
        int r  = tid >> 2;
        int c0 = (tid & 3) * 16;
        #pragma unroll
        for (int j = 0; j < 16; j += 4) {
            float4v f = *(const float4v*)&wo[(size_t)(k0 + r) * DMODEL + n0 + c0 + j];
            st[c0 + j + 0][r] = f2bf(f[0]);
            st[c0 + j + 1][r] = f2bf(f[1]);
            st[c0 + j + 2][r] = f2bf(f[2]);
            st[c0 + j + 3][r] = f2bf(f[3]);
        }
        __syncthreads();
        ushort* dst = qkv + ((size_t)(2 * (n0 + r) + (k0 >> 10))) * NQKV + 2048 + (k0 & 1023);
        *(short8*)&dst[c0]     = *(short8*)&st[r][c0];
        *(short8*)&dst[c0 + 8] = *(short8*)&st[r][c0 + 8];
        return;
    }

    int job = zz;
    int wave = tid >> 6, lane = tid & 63, quad = lane >> 4, l16 = lane & 15;
    int qt  = J_QT[job];
    int kt0 = J_K0[job];
    int kt1 = J_K1[job];
    int ph  = J_PH[job];
    int h0 = hy * 2;
    int kh = hy >> 1;
    int q0 = qt * 64;

    int srow = tid >> 2, scol = (tid & 3) * 8;

    ushort* qbase0 = qkv + ((size_t)(b * TT) + q0) * NQKV + h0 * DH;
    ushort* qbase1 = qbase0 + DH;
    #pragma unroll
    for (int dk = 0; dk < 4; dk++) {
        GLDS16(qbase0 + (size_t)srow * NQKV + dk * 32 + scol, shm + dk * 2048 + wave * 512);
        GLDS16(qbase1 + (size_t)srow * NQKV + dk * 32 + scol, shm + 16384 + dk * 2048 + wave * 512);
    }
    __syncthreads();
    bf16x8 qf0[4], qf1[4];
    #pragma unroll
    for (int dk = 0; dk < 4; dk++) {
        qf0[dk] = *(const bf16x8*)&shm[dk * 2048 + (wave * 16 + l16) * 32 + quad * 8];
        qf1[dk] = *(const bf16x8*)&shm[16384 + dk * 2048 + (wave * 16 + l16) * 32 + quad * 8];
    }
    __syncthreads();

    float4v O0[8], O1[8];
    #pragma unroll
    for (int i = 0; i < 8; i++) {
        O0[i] = (float4v){0.f, 0.f, 0.f, 0.f};
        O1[i] = (float4v){0.f, 0.f, 0.f, 0.f};
    }
    float m0r = -1e30f, l0r = 0.f;
    float m1r = -1e30f, l1r = 0.f;

    const float scale = 0.08838834764831845f;   // 1/sqrt(128)
    const float THRR  = 90.50966799f;           // 8/scale
    int qg = q0 + wave * 16 + l16;

    const ushort* kb2 = kbf  + ((size_t)(b * NKV + kh)) * TT * DH;
    const ushort* vb2 = vbfT + ((size_t)(b * NKV + kh)) * DH * TT;

    // per-wave P buffer (wave-private; no cross-wave sync needed)
    ushort* Pl = shm + 32768 + wave * 2048;     // [head 2][q 16][k 64] bf16
    int qsw = l16 & 7;

    auto stage = [&](int buf, int kt) {
        ushort* Kb = shm + buf * 16384;
        ushort* Vb = Kb + 8192;
        int k0 = kt * 64;
        #pragma unroll
        for (int dk = 0; dk < 4; dk++)
            GLDS16(kb2 + (size_t)(k0 + srow) * DH + dk * 32 + scol, Kb + dk * 2048 + wave * 512);
        #pragma unroll
        for (int kk = 0; kk < 2; kk++)
            #pragma unroll
            for (int p = 0; p < 2; p++)
                GLDS16(vb2 + (size_t)(p * 64 + srow) * TT + k0 + kk * 32 + scol,
                       Vb + kk * 4096 + (p * 64 + wave * 16) * 32);
    };

    stage(0, kt0);

    for (int kt = kt0; kt < kt1; kt++) {
        int cur = (kt - kt0) & 1;
        __syncthreads();
        if (kt + 1 < kt1)
            stage(cur ^ 1, kt + 1);

        const ushort* Kc = shm + cur * 16384;
        const ushort* Vc = Kc + 8192;
        int k0 = kt * 64;

        float4v s0[4], s1[4];
        __builtin_amdgcn_s_setprio(1);
        #pragma unroll
        for (int t2i = 0; t2i < 4; t2i++) {
            float4v a0 = (float4v){0.f, 0.f, 0.f, 0.f};
            float4v a1 = (float4v){0.f, 0.f, 0.f, 0.f};
            #pragma unroll
            for (int dk = 0; dk < 4; dk++) {
                bf16x8 af = *(const bf16x8*)&Kc[dk * 2048 + (t2i * 16 + l16) * 32 + quad * 8];
                a0 = __builtin_amdgcn_mfma_f32_16x16x32_bf16(af, qf0[dk], a0, 0, 0, 0);
                a1 = __builtin_amdgcn_mfma_f32_16x16x32_bf16(af, qf1[dk], a1, 0, 0, 0);
            }
            s0[t2i] = a0; s1[t2i] = a1;
        }
        __builtin_amdgcn_s_setprio(0);

        if ((q0 >= NV) && (kt == qt)) {
            #pragma unroll
            for (int t2i = 0; t2i < 4; t2i++)
                #pragma unroll
                for (int i = 0; i < 4; i++)
                    if (k0 + t2i * 16 + quad * 4 + i > qg) {
                        s0[t2i][i] = -1e9f;
                        s1[t2i][i] = -1e9f;
                    }
        }

        float mx0 = -1e30f, mx1 = -1e30f;
        #pragma unroll
        for (int t2i = 0; t2i < 4; t2i++)
            #pragma unroll
            for (int i = 0; i < 4; i++) {
                mx0 = fmaxf(mx0, s0[t2i][i]);
                mx1 = fmaxf(mx1, s1[t2i][i]);
            }
        mx0 = fmaxf(mx0, __shfl_xor(mx0, 16, 64));
        mx0 = fmaxf(mx0, __shfl_xor(mx0, 32, 64));
        mx1 = fmaxf(mx1, __shfl_xor(mx1, 16, 64));
        mx1 = fmaxf(mx1, __shfl_xor(mx1, 32, 64));

        bool skip0 = __all(mx0 <= m0r + THRR);
        bool skip1 = __all(mx1 <= m1r + THRR);
        float mn0 = fmaxf(m0r, mx0), mn1 = fmaxf(m1r, mx1);
        float mref0 = skip0 ? m0r : mn0;
        float mref1 = skip1 ? m1r : mn1;
        float nb0 = -mref0 * scale;
        float nb1 = -mref1 * scale;

        float ss0 = 0.f, ss1 = 0.f;
        #pragma unroll
        for (int t2i = 0; t2i < 4; t2i++)
            #pragma unroll
            for (int i = 0; i < 4; i++) {
                float p0 = __expf(__builtin_fmaf(s0[t2i][i], scale, nb0)); s0[t2i][i] = p0; ss0 += p0;
                float p1 = __expf(__builtin_fmaf(s1[t2i][i], scale, nb1)); s1[t2i][i] = p1; ss1 += p1;
            }
        ss0 += __shfl_xor(ss0, 16, 64); ss0 += __shfl_xor(ss0, 32, 64);
        ss1 += __shfl_xor(ss1, 16, 64); ss1 += __shfl_xor(ss1, 32, 64);

        if (!skip0) {
            float al0 = __expf((m0r - mn0) * scale);
            #pragma unroll
            for (int dt = 0; dt < 8; dt++)
                #pragma unroll
                for (int i = 0; i < 4; i++) O0[dt][i] *= al0;
            l0r *= al0;
            m0r = mn0;
        }
        l0r += ss0;
        if (!skip1) {
            float al1 = __expf((m1r - mn1) * scale);
            #pragma unroll
            for (int dt = 0; dt < 8; dt++)
                #pragma unroll
                for (int i = 0; i < 4; i++) O1[dt][i] *= al1;
            l1r *= al1;
            m1r = mn1;
        }
        l1r += ss1;

        // ---- P -> per-wave LDS (producer: lane holds P[t2i*16+quad*4+i][q=l16])
        #pragma unroll
        for (int t2i = 0; t2i < 4; t2i++) {
            int g = t2i * 2 + (quad >> 1);
            int base = l16 * 64 + ((g ^ qsw) << 3) + (quad & 1) * 4;
            *(unsigned*)&Pl[base]            = cvtpk(s0[t2i][0], s0[t2i][1]);
            *(unsigned*)&Pl[base + 2]        = cvtpk(s0[t2i][2], s0[t2i][3]);
            *(unsigned*)&Pl[1024 + base]     = cvtpk(s1[t2i][0], s1[t2i][1]);
            *(unsigned*)&Pl[1024 + base + 2] = cvtpk(s1[t2i][2], s1[t2i][3]);
        }

        // ---- PV: B-fragment = P[k = kk*32+quad*8+j][q=l16] as one b128 read
        #pragma unroll
        for (int kk = 0; kk < 2; kk++) {
            int gc = kk * 4 + quad;
            int raddr = l16 * 64 + ((gc ^ qsw) << 3);
            bf16x8 pf0 = *(const bf16x8*)&Pl[raddr];
            bf16x8 pf1 = *(const bf16x8*)&Pl[1024 + raddr];
            __builtin_amdgcn_s_setprio(1);
            #pragma unroll
            for (int dt = 0; dt < 8; dt++) {
                bf16x8 vf = *(const bf16x8*)&Vc[kk * 4096 + (dt * 16 + l16) * 32 + quad * 8];
                O0[dt] = __builtin_amdgcn_mfma_f32_16x16x32_bf16(vf, pf0, O0[dt], 0, 0, 0);
                O1[dt] = __builtin_amdgcn_mfma_f32_16x16x32_bf16(vf, pf1, O1[dt], 0, 0, 0);
            }
            __builtin_amdgcn_s_setprio(0);
        }
    }

    // epilogue: normalized O; whole jobs + half1 -> qkv, half0 -> scratch.
    float rinv0 = 1.f / l0r, rinv1 = 1.f / l1r;
    int qrow = wave * 16 + l16;
    if (ph == 255 || (ph & 1)) {
        size_t orow = (size_t)qrow * NQKV;
        #pragma unroll
        for (int dt = 0; dt < 8; dt++)
            #pragma unroll
            for (int i = 0; i < 4; i += 2) {
                unsigned pk0 = cvtpk(O0[dt][i] * rinv0, O0[dt][i + 1] * rinv0);
                unsigned pk1 = cvtpk(O1[dt][i] * rinv1, O1[dt][i + 1] * rinv1);
                *(unsigned*)&qbase0[orow + dt * 16 + quad * 4 + i] = pk0;
                *(unsigned*)&qbase1[orow + dt * 16 + quad * 4 + i] = pk1;
            }
    } else {
        int g = ((b * 8 + hy) * NSLOT) + (ph >> 1);
        ushort* pb = pO + (size_t)g * 16384 + qrow * 256;
        #pragma unroll
        for (int dt = 0; dt < 8; dt++)
            #pragma unroll
            for (int i = 0; i < 4; i += 2) {
                int d = dt * 16 + quad * 4 + i;
                *(unsigned*)&pb[d]       = cvtpk(O0[dt][i] * rinv0, O0[dt][i + 1] * rinv0);
                *(unsigned*)&pb[128 + d] = cvtpk(O1[dt][i] * rinv1, O1[dt][i + 1] * rinv1);
            }
    }
    if (ph != 255 && quad == 0) {
        int g = ((b * 8 + hy) * NSLOT) + (ph >> 1);
        int half = ph & 1;
        float* mlb = ml + (size_t)g * 512 + half * 256 + qrow * 2;
        mlb[0]   = m0r;  mlb[1]   = l0r;    // head 0
        mlb[128] = m1r;  mlb[129] = l1r;    // head 1
    }
}

// ---------------------------------------------------------------------------
// Combine split-KV halves: qkv = (w0*P0 + w1*P1), wi = e^{(mi-m)s}*li / Z.
// ---------------------------------------------------------------------------
__global__ __launch_bounds__(256) void combine_split(
    ushort* __restrict__ qkv, const ushort* __restrict__ pO,
    const float* __restrict__ ml)
{
    int g = blockIdx.x;
    int slice = g / NSLOT, local = g % NSLOT;
    int b = slice >> 3, hy = slice & 7;
    int qt = (local < 4) ? local : (13 + local);
    int h0 = hy * 2;
    int q0 = qt * 64;

    int t = threadIdx.x;
    int r = t >> 2, seg = t & 3;
    int head = seg >> 1;
    const float scale = 0.08838834764831845f;

    const float* mlg = ml + (size_t)g * 512;
    float m0 = mlg[0 * 256 + head * 128 + r * 2];
    float l0 = mlg[0 * 256 + head * 128 + r * 2 + 1];
    float m1 = mlg[1 * 256 + head * 128 + r * 2];
    float l1 = mlg[1 * 256 + head * 128 + r * 2 + 1];
    float mm = fmaxf(m0, m1);
    float w0 = __expf((m0 - mm) * scale) * l0;
    float w1 = __expf((m1 - mm) * scale) * l1;
    float inv = 1.f / (w0 + w1);
    float a0 = w0 * inv, a1 = w1 * inv;

    const ushort* p = pO + (size_t)g * 16384 + r * 256 + seg * 64;
    ushort* q = qkv + ((size_t)(b * TT + q0 + r)) * NQKV + (h0 + head) * DH + (seg & 1) * 64;

    #pragma unroll
    for (int j = 0; j < 64; j += 2) {
        unsigned u0 = *(const unsigned*)&p[j];
        unsigned u1 = *(const unsigned*)&q[j];
        float lo = bf2f((ushort)(u0 & 0xffff)) * a0 + bf2f((ushort)(u1 & 0xffff)) * a1;
        float hi2 = bf2f((ushort)(u0 >> 16)) * a0 + bf2f((ushort)(u1 >> 16)) * a1;
        *(unsigned*)&q[j] = cvtpk(lo, hi2);
    }
}

// ---------------------------------------------------------------------------
extern "C" void kernel_launch(void* const* d_in, const int* in_sizes, int n_in,
                              void* d_out, int out_size, void* d_ws, size_t ws_size,
                              hipStream_t stream) {
    const float* x    = (const float*)d_in[0];
    const float* cosp = (const float*)d_in[1];
    const float* sinp = (const float*)d_in[2];
    const float* wq   = (const float*)d_in[3];
    const float* wk   = (const float*)d_in[4];
    const float* wv   = (const float*)d_in[5];
    const float* wo   = (const float*)d_in[6];

    float* out  = (float*)d_out;                         // (B,T,DMODEL) f32
    float* kout = out + (size_t)BB * TT * DMODEL;        // (B,NKV,T,DH) f32
    float* vout = kout + (size_t)BB * NKV * TT * DH;

    ushort* sc    = (ushort*)d_out;
    ushort* wqkvT = sc;                                   // [3072][2048] bf16
    ushort* xbf   = sc + (size_t)NQKV * DMODEL;           // [4096][2048] bf16
    ushort* kbf   = sc + (size_t)NQKV * DMODEL;           // (B,NKV,T,DH) bf16
    ushort* vbfT  = kbf + (size_t)BB * NKV * TT * DH;     // (B,NKV,DH,T) bf16
    ushort* pO    = sc;                                   // aliases dead wqkvT
    float*  ml    = (float*)(sc + 15000000);              // dead xbf tail zone

    ushort* qkv = (ushort*)d_ws;

    const int M = BB * TT;  // 4096

    // convert_x + wtrans_all fused (4096 + 1536 blocks)
    prep<<<dim3(4096 + 1536), 256, 0, stream>>>(x, xbf, wq, wk, wv, wqkvT);

    gemm_lds<<<dim3(NQKV / 128, M / 128), 256, 0, stream>>>(
        xbf, DMODEL, wqkvT, qkv, NQKV, DMODEL);

    postproc<<<dim3(RQ_BLOCKS + RK_BLOCKS + 512), 256, 0, stream>>>(
        qkv, cosp, sinp, kout, vout, kbf, vbfT);

    // attention (z-slowest LPT order) + wtrans_wo tail blocks fused
    attn_kernel<<<dim3(NH / 2, BB, NJOB + WOJOBS), 256, 0, stream>>>(
        qkv, kbf, vbfT, pO, ml, wo);

    combine_split<<<dim3(16 * NSLOT), 256, 0, stream>>>(qkv, pO, ml);

    gemm_out<<<dim3(DMODEL / 128, M / 128), 256, 0, stream>>>(qkv, qkv + 2048, out);
}